// Round 3
// baseline (93.817 us; speedup 1.0000x reference)
//
#include <hip/hip_runtime.h>
#include <hip/hip_bf16.h>
#include <math.h>

#define TILE_X 16
#define TILE_Y 32
#define HALO_X 18
#define HALO_Y 34
#define NPIX   (HALO_X*HALO_Y)   // 612
#define NLVL   16
#define CMAX   720               // max corners per level: nx<=20, ny<=36

typedef float v2f __attribute__((ext_vector_type(2)));

// ---------------- prep kernel ----------------
// ws layout (floats): [0..16) res_tab,
// [32..32+3456) Wp[b][l][tap][o][2]  (channel-pair-interleaved fused weights)
__global__ __launch_bounds__(512) void prep_kernel(
    const float* __restrict__ s,        // (4,512)
    const float* __restrict__ weight,   // (3,32,3,3) = 864
    const float* __restrict__ affine_w, // (32,512)
    const float* __restrict__ affine_b, // (32,)
    float* __restrict__ ws)
{
    __shared__ float styles[128];
    __shared__ float dcoef[12];
    int tid = threadIdx.x;

    // styles[b*32+c] = dot(s[b,:], affine_w[c,:]) / sqrt(512) + affine_b[c]
    {
        int p = tid >> 2;      // 0..127 -> (b,c)
        int q = tid & 3;       // quarter of k-range
        int b = p >> 5, c = p & 31;
        const float4* sv = (const float4*)(s + b*512 + q*128);
        const float4* wv = (const float4*)(affine_w + c*512 + q*128);
        float acc = 0.f;
        #pragma unroll
        for (int k = 0; k < 32; ++k) {
            float4 a = sv[k], w = wv[k];
            acc += a.x*w.x + a.y*w.y + a.z*w.z + a.w*w.w;
        }
        acc += __shfl_xor(acc, 1);
        acc += __shfl_xor(acc, 2);
        if (q == 0)
            styles[p] = acc * 0.044194173824159216f + affine_b[c];
    }
    // res table — replicate numpy float64 math, cast to fp32
    if (tid < 16) {
        double g = exp((log(512.0) - log(16.0)) / 15.0);
        ws[tid] = (float)(16.0 * pow(g, (double)tid));
    }
    __syncthreads();

    if (tid < 12) {
        int b = tid / 3, o = tid % 3;
        float sum = 0.f;
        for (int c = 0; c < 32; ++c) {
            float st = styles[b*32 + c];
            #pragma unroll
            for (int k = 0; k < 9; ++k) {
                float w = weight[o*288 + c*9 + k] * st;
                sum = fmaf(w, w, sum);
            }
        }
        dcoef[tid] = 1.0f / sqrtf(sum + 1e-8f);
    }
    __syncthreads();

    // Wp[b][l][tap][o][p] = weight[o, 2l+p, tap] * styles[b, 2l+p] * dcoef[b, o]
    for (int t = tid; t < 4*864; t += 512) {
        int b   = t / 864, r = t % 864;
        int l   = r / 54;  int r2 = r % 54;
        int tap = r2 / 6;  int r3 = r2 % 6;
        int o   = r3 >> 1; int p  = r3 & 1;
        int c   = 2*l + p;
        ws[32 + t] = weight[o*288 + c*9 + tap] * styles[b*32 + c] * dcoef[b*3 + o];
    }
}

// ---------------- main fused kernel ----------------
struct LP { int ixlo, iylo, nx, ncorn; unsigned magic; };

__global__ __launch_bounds__(256, 7) void main_kernel(
    const float* __restrict__ tables,  // (4,16,65536,2)
    const float* __restrict__ ws,
    const float* __restrict__ bias,    // (3,)
    float* __restrict__ out)           // (4,3,512,512)
{
    __shared__ v2f feat2[2][NPIX];      // 9792 B  (level's 2 channels, dbuf)
    __shared__ v2f corners[2][CMAX];    // 11520 B (corner grid, dbuf)

    const int blk   = blockIdx.x;
    const int b     = blk >> 9;
    const int trem  = blk & 511;
    const int tileY = trem >> 5, tileX = trem & 31;   // 16 y-tiles, 32 x-tiles
    const int gx0 = tileX*TILE_X - 1, gy0 = tileY*TILE_Y - 1;
    const int tid = threadIdx.x;

    const int vx_lo = max(gx0, 0), vx_hi = min(gx0 + HALO_X - 1, 511);
    const int vy_lo = max(gy0, 0), vy_hi = min(gy0 + HALO_Y - 1, 511);

    const v2f* tbl_base = (const v2f*)tables;

    auto level_params = [&](float res) {
        LP lp;
        float r512 = res * (1.0f/512.0f);
        int xlo = (int)floorf((vx_lo + 0.5f) * r512);
        int xhi = (int)floorf((vx_hi + 0.5f) * r512);
        int ylo = (int)floorf((vy_lo + 0.5f) * r512);
        int yhi = (int)floorf((vy_hi + 0.5f) * r512);
        lp.ixlo = xlo; lp.iylo = ylo;
        lp.nx = xhi - xlo + 2;
        int ny = yhi - ylo + 2;
        lp.ncorn = lp.nx * ny;
        lp.magic = 65536u / (unsigned)lp.nx + 1u;   // exact for c<=736, nx<=36
        return lp;
    };

    auto issue_fetch = [&](int lvl, const LP& lp, v2f* regs, int* slots) {
        const v2f* tbl = tbl_base + ((size_t)((b << 4) + lvl) << 16);
        #pragma unroll
        for (int r = 0; r < 3; ++r) {
            int c = tid + (r << 8);
            slots[r] = -1;
            if (c < lp.ncorn) {
                unsigned row = ((unsigned)c * lp.magic) >> 16;
                unsigned col = (unsigned)c - row * (unsigned)lp.nx;
                unsigned cx = (unsigned)(lp.ixlo + (int)col);
                unsigned cy = (unsigned)(lp.iylo + (int)row);
                unsigned h  = cx ^ (cy * 2654435761u);
                regs[r]  = tbl[h & 65535u];
                slots[r] = c;
            }
        }
    };

    // conv state: 2 pixels per thread (y-pair), 3 output channels, packed pairs
    const int ty = tid >> 4;     // 0..15 -> output rows 2ty, 2ty+1
    const int tx = tid & 15;
    const float* W = ws + 32 + b*864;    // Wp[l][tap][o][2]; l stride 54
    v2f accP0[3], accP1[3];
    #pragma unroll
    for (int o = 0; o < 3; ++o) { accP0[o] = (v2f){0.f, 0.f}; accP1[o] = (v2f){0.f, 0.f}; }

    // ---- prologue: fetch level 0 corners ----
    float res_cur = ws[0];
    LP lp = level_params(res_cur);
    {
        v2f regs[3]; int slots[3];
        issue_fetch(0, lp, regs, slots);
        #pragma unroll
        for (int r = 0; r < 3; ++r)
            if (slots[r] >= 0) corners[0][slots[r]] = regs[r];
    }
    __syncthreads();

    #pragma unroll 2
    for (int l = 0; l < NLVL; ++l) {
        const int buf = l & 1;

        // prefetch level l+1 corners into registers (loads fly during bilinear)
        v2f regs[3]; int slots[3];
        slots[0] = slots[1] = slots[2] = -1;
        LP lpn; lpn.ixlo = 0; lpn.iylo = 0; lpn.nx = 2; lpn.ncorn = 0; lpn.magic = 32769u;
        float res_next = 0.f;
        if (l + 1 < NLVL) {
            res_next = ws[l + 1];
            lpn = level_params(res_next);
            issue_fetch(l + 1, lpn, regs, slots);
        }

        // bilinear features for level l -> feat2[buf]  (packed fp32 lerps)
        {
            const v2f* cbuf = corners[buf];
            float r512 = res_cur * (1.0f/512.0f);
            #pragma unroll
            for (int it = 0; it < 3; ++it) {
                int p = tid + (it << 8);
                if (p < NPIX) {
                    int hy = p / HALO_X, hx = p - hy*HALO_X;
                    int gy = gy0 + hy, gx = gx0 + hx;
                    v2f f = (v2f){0.f, 0.f};
                    if ((unsigned)gx < 512u && (unsigned)gy < 512u) {
                        float px = (gx + 0.5f) * r512;
                        float py = (gy + 0.5f) * r512;
                        float pxf = floorf(px), pyf = floorf(py);
                        float fx = px - pxf, fy = py - pyf;
                        int s00 = ((int)pyf - lp.iylo)*lp.nx + ((int)pxf - lp.ixlo);
                        v2f c00 = cbuf[s00],         c10 = cbuf[s00 + 1];
                        v2f c01 = cbuf[s00 + lp.nx], c11 = cbuf[s00 + lp.nx + 1];
                        v2f fxv = (v2f){fx, fx};
                        v2f fyv = (v2f){fy, fy};
                        v2f r0 = __builtin_elementwise_fma(fxv, c10 - c00, c00);
                        v2f r1 = __builtin_elementwise_fma(fxv, c11 - c01, c01);
                        f      = __builtin_elementwise_fma(fyv, r1 - r0, r0);
                    }
                    feat2[buf][p] = f;
                }
            }
        }

        // land prefetched corners (vmcnt drains here, after bilinear compute)
        #pragma unroll
        for (int r = 0; r < 3; ++r)
            if (slots[r] >= 0) corners[buf ^ 1][slots[r]] = regs[r];
        __syncthreads();

        // conv partial accumulation for this level's channel pair (packed fma)
        {
            const v2f* fb = feat2[buf] + (ty*2)*HALO_X + tx;
            v2f v[4][3];
            #pragma unroll
            for (int r = 0; r < 4; ++r) {
                v[r][0] = fb[r*HALO_X + 0];
                v[r][1] = fb[r*HALO_X + 1];
                v[r][2] = fb[r*HALO_X + 2];
            }
            const float* Wl = W + l*54;   // [tap][o][2]
            #pragma unroll
            for (int ky = 0; ky < 3; ++ky) {
                #pragma unroll
                for (int kx = 0; kx < 3; ++kx) {
                    const float* Wt = Wl + (ky*3 + kx)*6;
                    v2f f0 = v[ky][kx];       // output row 2ty
                    v2f f1 = v[ky + 1][kx];   // output row 2ty+1
                    #pragma unroll
                    for (int o = 0; o < 3; ++o) {
                        v2f wp = *(const v2f*)(Wt + o*2);
                        accP0[o] = __builtin_elementwise_fma(wp, f0, accP0[o]);
                        accP1[o] = __builtin_elementwise_fma(wp, f1, accP1[o]);
                    }
                }
            }
        }

        lp = lpn; res_cur = res_next;
    }

    // ---- epilogue: horizontal sum + bias, clamp, store ----
    float acc[6];
    #pragma unroll
    for (int o = 0; o < 3; ++o) {
        acc[o]     = accP0[o].x + accP0[o].y + bias[o];
        acc[3 + o] = accP1[o].x + accP1[o].y + bias[o];
    }
    #pragma unroll
    for (int i = 0; i < 6; ++i)
        acc[i] = fminf(fmaxf(acc[i], -256.f), 256.f);

    const int gx = tileX*TILE_X + tx;
    const int gy = tileY*TILE_Y + ty*2;
    const int base0 = (gy << 9) + gx;
    const int base1 = base0 + 512;
    const int ob = (b*3) << 18;
    out[ob           + base0] = acc[0];
    out[ob + (1<<18) + base0] = acc[1];
    out[ob + (2<<18) + base0] = acc[2];
    out[ob           + base1] = acc[3];
    out[ob + (1<<18) + base1] = acc[4];
    out[ob + (2<<18) + base1] = acc[5];
}

extern "C" void kernel_launch(void* const* d_in, const int* in_sizes, int n_in,
                              void* d_out, int out_size, void* d_ws, size_t ws_size,
                              hipStream_t stream) {
    const float* x        = (const float*)d_in[0];
    const float* s        = (const float*)d_in[1];
    const float* weight   = (const float*)d_in[2];
    const float* affine_w = (const float*)d_in[3];
    const float* affine_b = (const float*)d_in[4];
    const float* bias     = (const float*)d_in[5];
    float* outp = (float*)d_out;
    float* wsf  = (float*)d_ws;

    prep_kernel<<<1, 512, 0, stream>>>(s, weight, affine_w, affine_b, wsf);
    main_kernel<<<2048, 256, 0, stream>>>(x, wsf, bias, outp);
}

// Round 4
// 85.088 us; speedup vs baseline: 1.1026x; 1.1026x over previous
//
#include <hip/hip_runtime.h>
#include <hip/hip_bf16.h>
#include <math.h>

#define TILE_X 16
#define TILE_Y 32
#define HALO_X 18
#define HALO_Y 34
#define NPIX   (HALO_X*HALO_Y)   // 612
#define NLVL   16
#define CMAX   720               // max corners per level: nx<=20, ny<=36

typedef float v2f __attribute__((ext_vector_type(2)));

// ---------------- prep kernel ----------------
// ws layout (floats): [0..16) res_tab,
// [32..32+3456) Wp[b][l][tap][o][2]  (channel-pair-interleaved fused weights)
__global__ __launch_bounds__(512) void prep_kernel(
    const float* __restrict__ s,        // (4,512)
    const float* __restrict__ weight,   // (3,32,3,3) = 864
    const float* __restrict__ affine_w, // (32,512)
    const float* __restrict__ affine_b, // (32,)
    float* __restrict__ ws)
{
    __shared__ float styles[128];
    __shared__ float dcoef[12];
    int tid = threadIdx.x;

    // styles[b*32+c] = dot(s[b,:], affine_w[c,:]) / sqrt(512) + affine_b[c]
    {
        int p = tid >> 2;      // 0..127 -> (b,c)
        int q = tid & 3;       // quarter of k-range
        int b = p >> 5, c = p & 31;
        const float4* sv = (const float4*)(s + b*512 + q*128);
        const float4* wv = (const float4*)(affine_w + c*512 + q*128);
        float acc = 0.f;
        #pragma unroll
        for (int k = 0; k < 32; ++k) {
            float4 a = sv[k], w = wv[k];
            acc += a.x*w.x + a.y*w.y + a.z*w.z + a.w*w.w;
        }
        acc += __shfl_xor(acc, 1);
        acc += __shfl_xor(acc, 2);
        if (q == 0)
            styles[p] = acc * 0.044194173824159216f + affine_b[c];
    }
    // res table — replicate numpy float64 math, cast to fp32
    if (tid < 16) {
        double g = exp((log(512.0) - log(16.0)) / 15.0);
        ws[tid] = (float)(16.0 * pow(g, (double)tid));
    }
    __syncthreads();

    if (tid < 12) {
        int b = tid / 3, o = tid % 3;
        float sum = 0.f;
        for (int c = 0; c < 32; ++c) {
            float st = styles[b*32 + c];
            #pragma unroll
            for (int k = 0; k < 9; ++k) {
                float w = weight[o*288 + c*9 + k] * st;
                sum = fmaf(w, w, sum);
            }
        }
        dcoef[tid] = 1.0f / sqrtf(sum + 1e-8f);
    }
    __syncthreads();

    // Wp[b][l][tap][o][p] = weight[o, 2l+p, tap] * styles[b, 2l+p] * dcoef[b, o]
    for (int t = tid; t < 4*864; t += 512) {
        int b   = t / 864, r = t % 864;
        int l   = r / 54;  int r2 = r % 54;
        int tap = r2 / 6;  int r3 = r2 % 6;
        int o   = r3 >> 1; int p  = r3 & 1;
        int c   = 2*l + p;
        ws[32 + t] = weight[o*288 + c*9 + tap] * styles[b*32 + c] * dcoef[b*3 + o];
    }
}

// ---------------- main fused kernel ----------------
struct LP { int ixlo, iylo, nx, ncorn; unsigned magic; };

__global__ __launch_bounds__(256, 4) void main_kernel(
    const float* __restrict__ tables,  // (4,16,65536,2)
    const float* __restrict__ ws,
    const float* __restrict__ bias,    // (3,)
    float* __restrict__ out)           // (4,3,512,512)
{
    __shared__ v2f feat2[2][NPIX];      // 9792 B  (level's 2 channels, dbuf)
    __shared__ v2f corners[2][CMAX];    // 11520 B (corner grid, dbuf)

    const int blk   = blockIdx.x;
    const int b     = blk >> 9;
    const int trem  = blk & 511;
    const int tileY = trem >> 5, tileX = trem & 31;   // 16 y-tiles, 32 x-tiles
    const int gx0 = tileX*TILE_X - 1, gy0 = tileY*TILE_Y - 1;
    const int tid = threadIdx.x;

    const int vx_lo = max(gx0, 0), vx_hi = min(gx0 + HALO_X - 1, 511);
    const int vy_lo = max(gy0, 0), vy_hi = min(gy0 + HALO_Y - 1, 511);

    const v2f* tbl_base = (const v2f*)tables;

    auto level_params = [&](float res) {
        LP lp;
        float r512 = res * (1.0f/512.0f);
        int xlo = (int)floorf((vx_lo + 0.5f) * r512);
        int xhi = (int)floorf((vx_hi + 0.5f) * r512);
        int ylo = (int)floorf((vy_lo + 0.5f) * r512);
        int yhi = (int)floorf((vy_hi + 0.5f) * r512);
        lp.ixlo = xlo; lp.iylo = ylo;
        lp.nx = xhi - xlo + 2;
        int ny = yhi - ylo + 2;
        lp.ncorn = lp.nx * ny;
        lp.magic = 65536u / (unsigned)lp.nx + 1u;   // exact for c<=736, nx<=36
        return lp;
    };

    auto issue_fetch = [&](int lvl, const LP& lp, v2f* regs, int* slots) {
        const v2f* tbl = tbl_base + ((size_t)((b << 4) + lvl) << 16);
        #pragma unroll
        for (int r = 0; r < 3; ++r) {
            int c = tid + (r << 8);
            slots[r] = -1;
            if (c < lp.ncorn) {
                unsigned row = ((unsigned)c * lp.magic) >> 16;
                unsigned col = (unsigned)c - row * (unsigned)lp.nx;
                unsigned cx = (unsigned)(lp.ixlo + (int)col);
                unsigned cy = (unsigned)(lp.iylo + (int)row);
                unsigned h  = cx ^ (cy * 2654435761u);
                regs[r]  = tbl[h & 65535u];
                slots[r] = c;
            }
        }
    };

    // conv state: 2 pixels per thread (y-pair), 3 output channels, packed pairs
    const int ty = tid >> 4;     // 0..15 -> output rows 2ty, 2ty+1
    const int tx = tid & 15;
    const float* W = ws + 32 + b*864;    // Wp[l][tap][o][2]; l stride 54
    v2f accP0[3], accP1[3];
    #pragma unroll
    for (int o = 0; o < 3; ++o) { accP0[o] = (v2f){0.f, 0.f}; accP1[o] = (v2f){0.f, 0.f}; }

    // ---- prologue: fetch level 0 corners ----
    float res_cur = ws[0];
    LP lp = level_params(res_cur);
    {
        v2f regs[3]; int slots[3];
        issue_fetch(0, lp, regs, slots);
        #pragma unroll
        for (int r = 0; r < 3; ++r)
            if (slots[r] >= 0) corners[0][slots[r]] = regs[r];
    }
    __syncthreads();

    #pragma unroll 2
    for (int l = 0; l < NLVL; ++l) {
        const int buf = l & 1;

        // prefetch level l+1 corners into registers (loads fly during bilinear)
        v2f regs[3]; int slots[3];
        slots[0] = slots[1] = slots[2] = -1;
        LP lpn; lpn.ixlo = 0; lpn.iylo = 0; lpn.nx = 2; lpn.ncorn = 0; lpn.magic = 32769u;
        float res_next = 0.f;
        if (l + 1 < NLVL) {
            res_next = ws[l + 1];
            lpn = level_params(res_next);
            issue_fetch(l + 1, lpn, regs, slots);
        }

        // bilinear features for level l -> feat2[buf]  (packed fp32 lerps)
        {
            const v2f* cbuf = corners[buf];
            float r512 = res_cur * (1.0f/512.0f);
            #pragma unroll
            for (int it = 0; it < 3; ++it) {
                int p = tid + (it << 8);
                if (p < NPIX) {
                    int hy = p / HALO_X, hx = p - hy*HALO_X;
                    int gy = gy0 + hy, gx = gx0 + hx;
                    v2f f = (v2f){0.f, 0.f};
                    if ((unsigned)gx < 512u && (unsigned)gy < 512u) {
                        float px = (gx + 0.5f) * r512;
                        float py = (gy + 0.5f) * r512;
                        float pxf = floorf(px), pyf = floorf(py);
                        float fx = px - pxf, fy = py - pyf;
                        int s00 = ((int)pyf - lp.iylo)*lp.nx + ((int)pxf - lp.ixlo);
                        v2f c00 = cbuf[s00],         c10 = cbuf[s00 + 1];
                        v2f c01 = cbuf[s00 + lp.nx], c11 = cbuf[s00 + lp.nx + 1];
                        v2f fxv = (v2f){fx, fx};
                        v2f fyv = (v2f){fy, fy};
                        v2f r0 = __builtin_elementwise_fma(fxv, c10 - c00, c00);
                        v2f r1 = __builtin_elementwise_fma(fxv, c11 - c01, c01);
                        f      = __builtin_elementwise_fma(fyv, r1 - r0, r0);
                    }
                    feat2[buf][p] = f;
                }
            }
        }

        // land prefetched corners (vmcnt drains here, after bilinear compute)
        #pragma unroll
        for (int r = 0; r < 3; ++r)
            if (slots[r] >= 0) corners[buf ^ 1][slots[r]] = regs[r];
        __syncthreads();

        // conv partial accumulation for this level's channel pair (packed fma)
        {
            const v2f* fb = feat2[buf] + (ty*2)*HALO_X + tx;
            v2f v[4][3];
            #pragma unroll
            for (int r = 0; r < 4; ++r) {
                v[r][0] = fb[r*HALO_X + 0];
                v[r][1] = fb[r*HALO_X + 1];
                v[r][2] = fb[r*HALO_X + 2];
            }
            const float* Wl = W + l*54;   // [tap][o][2]
            #pragma unroll
            for (int ky = 0; ky < 3; ++ky) {
                #pragma unroll
                for (int kx = 0; kx < 3; ++kx) {
                    const float* Wt = Wl + (ky*3 + kx)*6;
                    v2f f0 = v[ky][kx];       // output row 2ty
                    v2f f1 = v[ky + 1][kx];   // output row 2ty+1
                    #pragma unroll
                    for (int o = 0; o < 3; ++o) {
                        v2f wp = *(const v2f*)(Wt + o*2);
                        accP0[o] = __builtin_elementwise_fma(wp, f0, accP0[o]);
                        accP1[o] = __builtin_elementwise_fma(wp, f1, accP1[o]);
                    }
                }
            }
        }

        lp = lpn; res_cur = res_next;
    }

    // ---- epilogue: horizontal sum + bias, clamp, store ----
    float acc[6];
    #pragma unroll
    for (int o = 0; o < 3; ++o) {
        acc[o]     = accP0[o].x + accP0[o].y + bias[o];
        acc[3 + o] = accP1[o].x + accP1[o].y + bias[o];
    }
    #pragma unroll
    for (int i = 0; i < 6; ++i)
        acc[i] = fminf(fmaxf(acc[i], -256.f), 256.f);

    const int gx = tileX*TILE_X + tx;
    const int gy = tileY*TILE_Y + ty*2;
    const int base0 = (gy << 9) + gx;
    const int base1 = base0 + 512;
    const int ob = (b*3) << 18;
    out[ob           + base0] = acc[0];
    out[ob + (1<<18) + base0] = acc[1];
    out[ob + (2<<18) + base0] = acc[2];
    out[ob           + base1] = acc[3];
    out[ob + (1<<18) + base1] = acc[4];
    out[ob + (2<<18) + base1] = acc[5];
}

extern "C" void kernel_launch(void* const* d_in, const int* in_sizes, int n_in,
                              void* d_out, int out_size, void* d_ws, size_t ws_size,
                              hipStream_t stream) {
    const float* x        = (const float*)d_in[0];
    const float* s        = (const float*)d_in[1];
    const float* weight   = (const float*)d_in[2];
    const float* affine_w = (const float*)d_in[3];
    const float* affine_b = (const float*)d_in[4];
    const float* bias     = (const float*)d_in[5];
    float* outp = (float*)d_out;
    float* wsf  = (float*)d_ws;

    prep_kernel<<<1, 512, 0, stream>>>(s, weight, affine_w, affine_b, wsf);
    main_kernel<<<2048, 256, 0, stream>>>(x, wsf, bias, outp);
}

// Round 5
// 73.985 us; speedup vs baseline: 1.2680x; 1.1501x over previous
//
#include <hip/hip_runtime.h>
#include <hip/hip_bf16.h>
#include <math.h>

#define TILE_X 16
#define TILE_Y 32
#define HALO_X 18
#define HALO_Y 34
#define NPIX   (HALO_X*HALO_Y)   // 612
#define NLVL   16
#define CMAX   720               // max corners per level (nx<=19, ny<=35 -> 665)

typedef float v2f __attribute__((ext_vector_type(2)));

// ---------------- prep kernel ----------------
// ws layout (floats): [0..16) res_tab (unused by main now, kept),
// [32..32+3456) Wp[b][l][tap][o][2]  (channel-pair-interleaved fused weights)
__global__ __launch_bounds__(512) void prep_kernel(
    const float* __restrict__ s,        // (4,512)
    const float* __restrict__ weight,   // (3,32,3,3) = 864
    const float* __restrict__ affine_w, // (32,512)
    const float* __restrict__ affine_b, // (32,)
    float* __restrict__ ws)
{
    __shared__ float styles[128];
    __shared__ float dcoef[12];
    int tid = threadIdx.x;

    {
        int p = tid >> 2;      // 0..127 -> (b,c)
        int q = tid & 3;       // quarter of k-range
        int b = p >> 5, c = p & 31;
        const float4* sv = (const float4*)(s + b*512 + q*128);
        const float4* wv = (const float4*)(affine_w + c*512 + q*128);
        float acc = 0.f;
        #pragma unroll
        for (int k = 0; k < 32; ++k) {
            float4 a = sv[k], w = wv[k];
            acc += a.x*w.x + a.y*w.y + a.z*w.z + a.w*w.w;
        }
        acc += __shfl_xor(acc, 1);
        acc += __shfl_xor(acc, 2);
        if (q == 0)
            styles[p] = acc * 0.044194173824159216f + affine_b[c];
    }
    if (tid < 16) {
        double g = exp((log(512.0) - log(16.0)) / 15.0);
        ws[tid] = (float)(16.0 * pow(g, (double)tid));
    }
    __syncthreads();

    if (tid < 12) {
        int b = tid / 3, o = tid % 3;
        float sum = 0.f;
        for (int c = 0; c < 32; ++c) {
            float st = styles[b*32 + c];
            #pragma unroll
            for (int k = 0; k < 9; ++k) {
                float w = weight[o*288 + c*9 + k] * st;
                sum = fmaf(w, w, sum);
            }
        }
        dcoef[tid] = 1.0f / sqrtf(sum + 1e-8f);
    }
    __syncthreads();

    // Wp[b][l][tap][o][p] = weight[o, 2l+p, tap] * styles[b, 2l+p] * dcoef[b, o]
    for (int t = tid; t < 4*864; t += 512) {
        int b   = t / 864, r = t % 864;
        int l   = r / 54;  int r2 = r % 54;
        int tap = r2 / 6;  int r3 = r2 % 6;
        int o   = r3 >> 1; int p  = r3 & 1;
        int c   = 2*l + p;
        ws[32 + t] = weight[o*288 + c*9 + tap] * styles[b*32 + c] * dcoef[b*3 + o];
    }
}

// ---------------- main fused kernel ----------------
struct LP { int ixlo, iylo, nx, ncorn; unsigned magic; float r512; };

__global__ __launch_bounds__(256, 4) void main_kernel(
    const float* __restrict__ tables,  // (4,16,65536,2)
    const float* __restrict__ ws,
    const float* __restrict__ bias,    // (3,)
    float* __restrict__ out)           // (4,3,512,512)
{
    __shared__ v2f feat2[2][NPIX];      // 9792 B
    __shared__ v2f corners[3][CMAX];    // 17280 B (triple-buffered, 2-deep prefetch)

    const int blk   = blockIdx.x;
    const int b     = blk >> 9;
    const int trem  = blk & 511;
    const int tileY = trem >> 5, tileX = trem & 31;
    const int gx0 = tileX*TILE_X - 1, gy0 = tileY*TILE_Y - 1;
    const int tid = threadIdx.x;

    const int vx_lo = max(gx0, 0), vx_hi = min(gx0 + HALO_X - 1, 511);
    const int vy_lo = max(gy0, 0), vy_hi = min(gy0 + HALO_Y - 1, 511);

    const v2f* tbl_base = (const v2f*)tables;

    // res(l) = 16 * 2^(l/3): growth = exp(ln(32)/15) = 2^(1/3) exactly.
    // Exact at integer-power levels; elsewhere <=2ulp off the fp64 table,
    // harmless since bilinear is continuous across cell boundaries.
    auto level_params = [&](int l) {
        LP lp;
        float res = 16.0f * exp2f((float)l * (1.0f/3.0f));
        lp.r512 = res * (1.0f/512.0f);
        int xlo = (int)floorf((vx_lo + 0.5f) * lp.r512);
        int xhi = (int)floorf((vx_hi + 0.5f) * lp.r512);
        int ylo = (int)floorf((vy_lo + 0.5f) * lp.r512);
        int yhi = (int)floorf((vy_hi + 0.5f) * lp.r512);
        lp.ixlo = xlo; lp.iylo = ylo;
        lp.nx = xhi - xlo + 2;
        int ny = yhi - ylo + 2;
        lp.ncorn = lp.nx * ny;
        lp.magic = 65536u / (unsigned)lp.nx + 1u;
        return lp;
    };

    auto issue_fetch = [&](int lvl, const LP& lp, v2f* regs, int* slots) {
        const v2f* tbl = tbl_base + ((size_t)((b << 4) + lvl) << 16);
        #pragma unroll
        for (int r = 0; r < 3; ++r) {
            int c = tid + (r << 8);
            slots[r] = -1;
            if (c < lp.ncorn) {
                unsigned row = ((unsigned)c * lp.magic) >> 16;
                unsigned col = (unsigned)c - row * (unsigned)lp.nx;
                unsigned cx = (unsigned)(lp.ixlo + (int)col);
                unsigned cy = (unsigned)(lp.iylo + (int)row);
                unsigned h  = cx ^ (cy * 2654435761u);
                regs[r]  = tbl[h & 65535u];
                slots[r] = c;
            }
        }
    };

    const int ty = tid >> 4;     // output rows 2ty, 2ty+1
    const int tx = tid & 15;
    const float* W = ws + 32 + b*864;    // Wp[l][tap][o][2]; l stride 54
    v2f accP0[3], accP1[3];
    #pragma unroll
    for (int o = 0; o < 3; ++o) { accP0[o] = (v2f){0.f, 0.f}; accP1[o] = (v2f){0.f, 0.f}; }

    auto bilinear_phase = [&](int l, const LP& lp) {
        const v2f* cbuf = corners[l % 3];
        v2f* fout = feat2[l & 1];
        #pragma unroll
        for (int it = 0; it < 3; ++it) {
            int p = tid + (it << 8);
            if (p < NPIX) {
                int hy = p / HALO_X, hx = p - hy*HALO_X;
                int gy = gy0 + hy, gx = gx0 + hx;
                v2f f = (v2f){0.f, 0.f};
                if ((unsigned)gx < 512u && (unsigned)gy < 512u) {
                    float px = (gx + 0.5f) * lp.r512;
                    float py = (gy + 0.5f) * lp.r512;
                    float pxf = floorf(px), pyf = floorf(py);
                    float fx = px - pxf, fy = py - pyf;
                    int s00 = ((int)pyf - lp.iylo)*lp.nx + ((int)pxf - lp.ixlo);
                    v2f c00 = cbuf[s00],         c10 = cbuf[s00 + 1];
                    v2f c01 = cbuf[s00 + lp.nx], c11 = cbuf[s00 + lp.nx + 1];
                    v2f fxv = (v2f){fx, fx};
                    v2f fyv = (v2f){fy, fy};
                    v2f r0 = __builtin_elementwise_fma(fxv, c10 - c00, c00);
                    v2f r1 = __builtin_elementwise_fma(fxv, c11 - c01, c01);
                    f      = __builtin_elementwise_fma(fyv, r1 - r0, r0);
                }
                fout[p] = f;
            }
        }
    };

    auto conv_phase = [&](int l) {
        const v2f* fb = feat2[l & 1] + (ty*2)*HALO_X + tx;
        v2f v[4][3];
        #pragma unroll
        for (int r = 0; r < 4; ++r) {
            v[r][0] = fb[r*HALO_X + 0];
            v[r][1] = fb[r*HALO_X + 1];
            v[r][2] = fb[r*HALO_X + 2];
        }
        const float* Wl = W + l*54;   // [tap][o][2]
        #pragma unroll
        for (int ky = 0; ky < 3; ++ky) {
            #pragma unroll
            for (int kx = 0; kx < 3; ++kx) {
                const float* Wt = Wl + (ky*3 + kx)*6;
                v2f f0 = v[ky][kx];
                v2f f1 = v[ky + 1][kx];
                #pragma unroll
                for (int o = 0; o < 3; ++o) {
                    v2f wp = *(const v2f*)(Wt + o*2);
                    accP0[o] = __builtin_elementwise_fma(wp, f0, accP0[o]);
                    accP1[o] = __builtin_elementwise_fma(wp, f1, accP1[o]);
                }
            }
        }
    };

    // parity register sets: gather data for level k lives in set (k&1)
    v2f regs0[3], regs1[3];
    int slots0[3], slots1[3];

    auto land = [&](int lvl, v2f* regs, int* slots) {
        v2f* cb = corners[lvl % 3];
        #pragma unroll
        for (int r = 0; r < 3; ++r)
            if (slots[r] >= 0) cb[slots[r]] = regs[r];
    };

    // ---- prologue ----
    LP lpC = level_params(0);
    {
        v2f rg[3]; int sl[3];
        issue_fetch(0, lpC, rg, sl);
        land(0, rg, sl);
    }
    LP lpN1 = level_params(1);
    issue_fetch(1, lpN1, regs1, slots1);     // G(1) -> set1
    __syncthreads();

    // ---- main loop: l = 0..13 (14 = 2*7, parity static under unroll 2) ----
    #pragma unroll 2
    for (int l = 0; l < 14; ++l) {
        LP lpN2 = level_params(l + 2);
        if ((l & 1) == 0) issue_fetch(l + 2, lpN2, regs0, slots0);   // G(l+2) -> set[l&1]
        else              issue_fetch(l + 2, lpN2, regs1, slots1);

        bilinear_phase(l, lpC);

        if ((l & 1) == 0) land(l + 1, regs1, slots1);   // G(l+1) from set[(l+1)&1]
        else              land(l + 1, regs0, slots0);
        __syncthreads();

        conv_phase(l);

        lpC = lpN1; lpN1 = lpN2;
    }

    // ---- epilogue: l = 14 (land G15 from set1), l = 15 ----
    bilinear_phase(14, lpC);
    land(15, regs1, slots1);
    __syncthreads();
    conv_phase(14);

    bilinear_phase(15, lpN1);
    __syncthreads();
    conv_phase(15);

    // ---- store ----
    float acc[6];
    #pragma unroll
    for (int o = 0; o < 3; ++o) {
        acc[o]     = accP0[o].x + accP0[o].y + bias[o];
        acc[3 + o] = accP1[o].x + accP1[o].y + bias[o];
    }
    #pragma unroll
    for (int i = 0; i < 6; ++i)
        acc[i] = fminf(fmaxf(acc[i], -256.f), 256.f);

    const int gx = tileX*TILE_X + tx;
    const int gy = tileY*TILE_Y + ty*2;
    const int base0 = (gy << 9) + gx;
    const int base1 = base0 + 512;
    const int ob = (b*3) << 18;
    out[ob           + base0] = acc[0];
    out[ob + (1<<18) + base0] = acc[1];
    out[ob + (2<<18) + base0] = acc[2];
    out[ob           + base1] = acc[3];
    out[ob + (1<<18) + base1] = acc[4];
    out[ob + (2<<18) + base1] = acc[5];
}

extern "C" void kernel_launch(void* const* d_in, const int* in_sizes, int n_in,
                              void* d_out, int out_size, void* d_ws, size_t ws_size,
                              hipStream_t stream) {
    const float* x        = (const float*)d_in[0];
    const float* s        = (const float*)d_in[1];
    const float* weight   = (const float*)d_in[2];
    const float* affine_w = (const float*)d_in[3];
    const float* affine_b = (const float*)d_in[4];
    const float* bias     = (const float*)d_in[5];
    float* outp = (float*)d_out;
    float* wsf  = (float*)d_ws;

    prep_kernel<<<1, 512, 0, stream>>>(s, weight, affine_w, affine_b, wsf);
    main_kernel<<<2048, 256, 0, stream>>>(x, wsf, bias, outp);
}